// Round 2
// baseline (623.754 us; speedup 1.0000x reference)
//
#include <hip/hip_runtime.h>
#include <math.h>

// EdgeEmbeddingBlock: out_r[e,k,n,j] = radial[e,n] * na[sender[e],k] * ylm_r[e,j]
//                     out_i[e,k,n,j] = radial[e,n] * na[sender[e],k] * ylm_i[e,j]
// Constants: E=60000, N_NODES=4000, K_ATTR=10, NMAX=8, J=16 (LMAX=3),
// R_CUT=5, P_CUT=6.
//
// ALL I/O IS FLOAT32 (reference dtypes; edge_index int32).
//
// Output = 2 * 60000*10*8*16 f32 = 614.4 MB -> pure streaming writes.
// Round-0 theory: 641 us == 0.96 TB/s effective, ~15% of HBM. Write-only
// kernel with coalesced 1KiB/wave-instr stores should be near write BW
// (~150-200 us). Suspect L2 write-allocate thrash on the 614 MB stream
// -> NONTEMPORAL stores (evict-first hint, global_store_dwordx4 nt).
// Round 1: __builtin_nontemporal_store requires a clang ext_vector type,
// not HIP's float4 class -> use f32x4 typedef.
//
// Mapping: one wave per edge. Per-edge r/i each = 1280 f32 = 320 chunks of
// 4 f32 (16 B). chunk c = lane + 64*it = k*32 + n*4 + jq with
// jq=lane&3, n=(lane>>2)&7, kh=lane>>5 (all lane-fixed), k=kh+2*it, it=0..4
// -> covers k in [0,10) exactly. Two dwordx4 nt-stores per lane per iter.

#define E_CONST 60000
#define N_NODES 4000
#define K_ATTR 10
#define PER_EDGE 1280  // K_ATTR*8*16

typedef float f32x4 __attribute__((ext_vector_type(4)));

__global__ __launch_bounds__(256) void edge_embed_kernel(
    const int* __restrict__ edge_index,
    const float* __restrict__ lengths,
    const float* __restrict__ vecs,
    const float* __restrict__ attrs,
    float* __restrict__ out)
{
    const int wid = (blockIdx.x * blockDim.x + threadIdx.x) >> 6;
    if (wid >= E_CONST) return;
    const int lane = threadIdx.x & 63;
    const int e = wid;

    // ---- per-edge loads (wave-uniform addresses -> broadcast) ----
    const float x  = lengths[e];
    const float vx = vecs[3*e + 0];
    const float vy = vecs[3*e + 1];
    const float vz = vecs[3*e + 2];
    int sender = edge_index[e];                 // row 0 of (2,E), int32
    sender = min(max(sender, 0), N_NODES - 1);  // safety clamp

    // ---- lane's fixed (jq, n, kh) ----
    const int jq = lane & 3;         // j-quad: j = 4*jq .. 4*jq+3
    const int n  = (lane >> 2) & 7;  // radial index
    const int kh = lane >> 5;        // k = kh + 2*it

    // ---- prefetch this lane's 5 attr values early (overlap latency) ----
    float na[5];
#pragma unroll
    for (int it = 0; it < 5; ++it)
        na[it] = attrs[sender * K_ATTR + (kh + 2 * it)];

    // ---- radial for this lane's n ----
    const float u  = x * 0.2f;                                // x / R_CUT
    const float u2 = u * u, u3 = u2 * u;
    const float u6 = u3 * u3, u7 = u6 * u, u8 = u7 * u;
    float env = 1.0f - 28.0f * u6 + 48.0f * u7 - 21.0f * u8;  // p=6 poly cutoff
    env = (u < 1.0f) ? env : 0.0f;
    const float PREF = 0.63245553203367586f;                  // sqrt(2/5)
    const float w = (float)(n + 1) * 0.6283185307179586f;     // (n+1)*pi/5
    const float rad = PREF * sinf(w * x) / x * env;

    // ---- unit direction ----
    const float nrm = sqrtf(vx*vx + vy*vy + vz*vz);
    const float inv = 1.0f / fmaxf(nrm, 1e-9f);
    const float ux = vx * inv, uy = vy * inv, uz = vz * inv;
    const float z = uz, z2 = z * z;

    // c_m = st^m cos(m phi), s_m = st^m sin(m phi); st*cosphi=ux, st*sinphi=uy
    const float c1 = ux,            s1 = uy;
    const float c2 = c1*ux - s1*uy, s2 = s1*ux + c1*uy;
    const float c3 = c2*ux - s2*uy, s3 = s2*ux + c2*uy;

    // Q[l,m] = P[l,m]/st^m (polynomials in z)
    const float Q10 = z;
    const float Q20 = 1.5f*z2 - 0.5f;
    const float Q21 = -3.0f*z;
    const float Q30 = (2.5f*z2 - 1.5f)*z;
    const float Q31 = 1.5f - 7.5f*z2;
    const float Q32 = 15.0f*z;

    // normalization nlm = sqrt((2l+1)/(4pi) * (l-|m|)!/(l+|m|)!)
    const float n00 = 0.28209479177387814f;
    const float n10 = 0.4886025119029199f,  n11 = 0.34549414947133544f;
    const float n20 = 0.6307831305050401f,  n21 = 0.2575161346821595f,  n22 = 0.12875806798063624f;
    const float n30 = 0.7463526651802308f,  n31 = 0.2154534560075959f,  n32 = 0.06813236509555449f, n33 = 0.027814921575518937f;

    // base(l,|m|): br = nlm*Q*c_m, bi = nlm*Q*s_m  (|m| >= 1)
    const float b1r  = n11 * (-1.0f) * c1, b1i  = n11 * (-1.0f) * s1;
    const float b21r = n21 * Q21 * c1,     b21i = n21 * Q21 * s1;
    const float b22r = n22 * 3.0f * c2,    b22i = n22 * 3.0f * s2;
    const float b31r = n31 * Q31 * c1,     b31i = n31 * Q31 * s1;
    const float b32r = n32 * Q32 * c2,     b32i = n32 * Q32 * s2;
    const float b33r = n33 * (-15.0f)*c3,  b33i = n33 * (-15.0f)*s3;

    // j ordering: l=0..3, m=-l..l.  m<0: s=(-1)^|m|, re=s*br, im=-s*bi.
    float yr[16], yi[16];
    yr[0]  =  n00;        yi[0]  =  0.0f;
    yr[1]  = -b1r;        yi[1]  =  b1i;    // (1,-1)
    yr[2]  =  n10 * Q10;  yi[2]  =  0.0f;   // (1, 0)
    yr[3]  =  b1r;        yi[3]  =  b1i;    // (1, 1)
    yr[4]  =  b22r;       yi[4]  = -b22i;   // (2,-2)
    yr[5]  = -b21r;       yi[5]  =  b21i;   // (2,-1)
    yr[6]  =  n20 * Q20;  yi[6]  =  0.0f;   // (2, 0)
    yr[7]  =  b21r;       yi[7]  =  b21i;   // (2, 1)
    yr[8]  =  b22r;       yi[8]  =  b22i;   // (2, 2)
    yr[9]  = -b33r;       yi[9]  =  b33i;   // (3,-3)
    yr[10] =  b32r;       yi[10] = -b32i;   // (3,-2)
    yr[11] = -b31r;       yi[11] =  b31i;   // (3,-1)
    yr[12] =  n30 * Q30;  yi[12] =  0.0f;   // (3, 0)
    yr[13] =  b31r;       yi[13] =  b31i;   // (3, 1)
    yr[14] =  b32r;       yi[14] =  b32i;   // (3, 2)
    yr[15] =  b33r;       yi[15] =  b33i;   // (3, 3)

    // select this lane's j-quad (jq loop-invariant -> cndmask tree)
    float ysr[4], ysi[4];
#pragma unroll
    for (int t = 0; t < 4; ++t) {
        const float r01 = (jq & 1) ? yr[4 + t]  : yr[t];
        const float r23 = (jq & 1) ? yr[12 + t] : yr[8 + t];
        const float i01 = (jq & 1) ? yi[4 + t]  : yi[t];
        const float i23 = (jq & 1) ? yi[12 + t] : yi[8 + t];
        ysr[t] = (jq & 2) ? r23 : r01;
        ysi[t] = (jq & 2) ? i23 : i01;
    }

    const size_t base_r = (size_t)e * PER_EDGE;
    const size_t base_i = (size_t)E_CONST * PER_EDGE + base_r;

#pragma unroll
    for (int it = 0; it < 5; ++it) {
        const float s = rad * na[it];
        const int c = lane + 64 * it;              // chunk (4-f32 units)
        const size_t off = (size_t)c * 4;

        f32x4 pr, pi;
        pr.x = s * ysr[0]; pr.y = s * ysr[1]; pr.z = s * ysr[2]; pr.w = s * ysr[3];
        pi.x = s * ysi[0]; pi.y = s * ysi[1]; pi.z = s * ysi[2]; pi.w = s * ysi[3];
        __builtin_nontemporal_store(pr, reinterpret_cast<f32x4*>(out + base_r + off));
        __builtin_nontemporal_store(pi, reinterpret_cast<f32x4*>(out + base_i + off));
    }
}

extern "C" void kernel_launch(void* const* d_in, const int* in_sizes, int n_in,
                              void* d_out, int out_size, void* d_ws, size_t ws_size,
                              hipStream_t stream) {
    const int*   edge_index = (const int*)d_in[0];
    const float* lengths    = (const float*)d_in[1];
    const float* vecs       = (const float*)d_in[2];
    const float* attrs      = (const float*)d_in[3];
    float*       out        = (float*)d_out;

    const int blocks = E_CONST / 4;   // 4 waves/block, 1 wave/edge
    edge_embed_kernel<<<blocks, 256, 0, stream>>>(edge_index, lengths, vecs, attrs, out);
}

// Round 3
// 616.914 us; speedup vs baseline: 1.0111x; 1.0111x over previous
//
#include <hip/hip_runtime.h>
#include <math.h>

// EdgeEmbeddingBlock: out_r[e,k,n,j] = radial[e,n] * na[sender[e],k] * ylm_r[e,j]
//                     out_i[e,k,n,j] = radial[e,n] * na[sender[e],k] * ylm_i[e,j]
// Constants: E=60000, N_NODES=4000, K_ATTR=10, NMAX=8, J=16 (LMAX=3),
// R_CUT=5, P_CUT=6.  ALL I/O FLOAT32 (edge_index int32).
//
// Output = 614.4 MB pure streaming writes. Harness fillBuffer runs 6.2 TB/s
// on the same buffer; our round-2 kernel ~230 us ~= 2.7 TB/s. Theory: wave
// churn — 60000 short waves, each load-chain -> compute -> only 10 stores
// -> retire. Round 3: 4 EDGES PER WAVE (15000 waves): all 4 edges' scalar
// inputs (incl. dependent attrs gather) loaded up front, then 4x(compute +
// 10 nt stores) = 40 back-to-back 1KiB stores/wave, load latency of edges
// 1-3 hidden under edge-0 work.
//
// Per-edge mapping (unchanged, verified): lane covers chunk c = lane+64*it,
// c = k*32 + n*4 + jq with jq=lane&3, n=(lane>>2)&7, kh=lane>>5, k=kh+2*it,
// it=0..4 -> k in [0,10). Two dwordx4 nt-stores per lane per iter.

#define E_CONST 60000
#define N_NODES 4000
#define K_ATTR 10
#define PER_EDGE 1280  // K_ATTR*8*16
#define EPW 4          // edges per wave

typedef float f32x4 __attribute__((ext_vector_type(4)));

__global__ __launch_bounds__(256) void edge_embed_kernel(
    const int* __restrict__ edge_index,
    const float* __restrict__ lengths,
    const float* __restrict__ vecs,
    const float* __restrict__ attrs,
    float* __restrict__ out)
{
    const int wid = (blockIdx.x * blockDim.x + threadIdx.x) >> 6;
    const int base_e = wid * EPW;
    if (base_e >= E_CONST) return;
    const int lane = threadIdx.x & 63;

    // ---- lane's fixed (jq, n, kh) ----
    const int jq = lane & 3;         // j-quad: j = 4*jq .. 4*jq+3
    const int n  = (lane >> 2) & 7;  // radial index
    const int kh = lane >> 5;        // k = kh + 2*it

    // ---- load ALL 4 edges' scalars first (hide the dependent chains) ----
    float xe[EPW], vxe[EPW], vye[EPW], vze[EPW];
    int snd[EPW];
#pragma unroll
    for (int i = 0; i < EPW; ++i) {
        const int e = base_e + i;
        xe[i]  = lengths[e];
        vxe[i] = vecs[3*e + 0];
        vye[i] = vecs[3*e + 1];
        vze[i] = vecs[3*e + 2];
        int s = edge_index[e];                  // row 0 of (2,E)
        snd[i] = min(max(s, 0), N_NODES - 1);   // safety clamp
    }
    float nae[EPW][5];
#pragma unroll
    for (int i = 0; i < EPW; ++i)
#pragma unroll
        for (int it = 0; it < 5; ++it)
            nae[i][it] = attrs[snd[i] * K_ATTR + (kh + 2 * it)];

    // normalization nlm = sqrt((2l+1)/(4pi) * (l-|m|)!/(l+|m|)!)
    const float n00 = 0.28209479177387814f;
    const float n10 = 0.4886025119029199f,  n11 = 0.34549414947133544f;
    const float n20 = 0.6307831305050401f,  n21 = 0.2575161346821595f,  n22 = 0.12875806798063624f;
    const float n30 = 0.7463526651802308f,  n31 = 0.2154534560075959f,  n32 = 0.06813236509555449f, n33 = 0.027814921575518937f;

#pragma unroll
    for (int i = 0; i < EPW; ++i) {
        const int e = base_e + i;
        const float x = xe[i];

        // ---- radial for this lane's n ----
        const float u  = x * 0.2f;                                // x / R_CUT
        const float u2 = u * u, u3 = u2 * u;
        const float u6 = u3 * u3, u7 = u6 * u, u8 = u7 * u;
        float env = 1.0f - 28.0f * u6 + 48.0f * u7 - 21.0f * u8;  // p=6 poly cutoff
        env = (u < 1.0f) ? env : 0.0f;
        const float PREF = 0.63245553203367586f;                  // sqrt(2/5)
        const float w = (float)(n + 1) * 0.6283185307179586f;     // (n+1)*pi/5
        const float rad = PREF * sinf(w * x) / x * env;

        // ---- unit direction ----
        const float vx = vxe[i], vy = vye[i], vz = vze[i];
        const float nrm = sqrtf(vx*vx + vy*vy + vz*vz);
        const float inv = 1.0f / fmaxf(nrm, 1e-9f);
        const float ux = vx * inv, uy = vy * inv, uz = vz * inv;
        const float z = uz, z2 = z * z;

        // c_m = st^m cos(m phi), s_m = st^m sin(m phi)
        const float c1 = ux,            s1 = uy;
        const float c2 = c1*ux - s1*uy, s2 = s1*ux + c1*uy;
        const float c3 = c2*ux - s2*uy, s3 = s2*ux + c2*uy;

        // Q[l,m] = P[l,m]/st^m (polynomials in z)
        const float Q10 = z;
        const float Q20 = 1.5f*z2 - 0.5f;
        const float Q21 = -3.0f*z;
        const float Q30 = (2.5f*z2 - 1.5f)*z;
        const float Q31 = 1.5f - 7.5f*z2;
        const float Q32 = 15.0f*z;

        // base(l,|m|): br = nlm*Q*c_m, bi = nlm*Q*s_m  (|m| >= 1)
        const float b1r  = n11 * (-1.0f) * c1, b1i  = n11 * (-1.0f) * s1;
        const float b21r = n21 * Q21 * c1,     b21i = n21 * Q21 * s1;
        const float b22r = n22 * 3.0f * c2,    b22i = n22 * 3.0f * s2;
        const float b31r = n31 * Q31 * c1,     b31i = n31 * Q31 * s1;
        const float b32r = n32 * Q32 * c2,     b32i = n32 * Q32 * s2;
        const float b33r = n33 * (-15.0f)*c3,  b33i = n33 * (-15.0f)*s3;

        // j ordering: l=0..3, m=-l..l.  m<0: s=(-1)^|m|, re=s*br, im=-s*bi.
        float yr[16], yi[16];
        yr[0]  =  n00;        yi[0]  =  0.0f;
        yr[1]  = -b1r;        yi[1]  =  b1i;    // (1,-1)
        yr[2]  =  n10 * Q10;  yi[2]  =  0.0f;   // (1, 0)
        yr[3]  =  b1r;        yi[3]  =  b1i;    // (1, 1)
        yr[4]  =  b22r;       yi[4]  = -b22i;   // (2,-2)
        yr[5]  = -b21r;       yi[5]  =  b21i;   // (2,-1)
        yr[6]  =  n20 * Q20;  yi[6]  =  0.0f;   // (2, 0)
        yr[7]  =  b21r;       yi[7]  =  b21i;   // (2, 1)
        yr[8]  =  b22r;       yi[8]  =  b22i;   // (2, 2)
        yr[9]  = -b33r;       yi[9]  =  b33i;   // (3,-3)
        yr[10] =  b32r;       yi[10] = -b32i;   // (3,-2)
        yr[11] = -b31r;       yi[11] =  b31i;   // (3,-1)
        yr[12] =  n30 * Q30;  yi[12] =  0.0f;   // (3, 0)
        yr[13] =  b31r;       yi[13] =  b31i;   // (3, 1)
        yr[14] =  b32r;       yi[14] =  b32i;   // (3, 2)
        yr[15] =  b33r;       yi[15] =  b33i;   // (3, 3)

        // select this lane's j-quad (jq loop-invariant -> cndmask tree)
        float ysr[4], ysi[4];
#pragma unroll
        for (int t = 0; t < 4; ++t) {
            const float r01 = (jq & 1) ? yr[4 + t]  : yr[t];
            const float r23 = (jq & 1) ? yr[12 + t] : yr[8 + t];
            const float i01 = (jq & 1) ? yi[4 + t]  : yi[t];
            const float i23 = (jq & 1) ? yi[12 + t] : yi[8 + t];
            ysr[t] = (jq & 2) ? r23 : r01;
            ysi[t] = (jq & 2) ? i23 : i01;
        }

        const size_t base_r = (size_t)e * PER_EDGE;
        const size_t base_i = (size_t)E_CONST * PER_EDGE + base_r;

#pragma unroll
        for (int it = 0; it < 5; ++it) {
            const float s = rad * nae[i][it];
            const int c = lane + 64 * it;              // chunk (4-f32 units)
            const size_t off = (size_t)c * 4;

            f32x4 pr, pi;
            pr.x = s * ysr[0]; pr.y = s * ysr[1]; pr.z = s * ysr[2]; pr.w = s * ysr[3];
            pi.x = s * ysi[0]; pi.y = s * ysi[1]; pi.z = s * ysi[2]; pi.w = s * ysi[3];
            __builtin_nontemporal_store(pr, reinterpret_cast<f32x4*>(out + base_r + off));
            __builtin_nontemporal_store(pi, reinterpret_cast<f32x4*>(out + base_i + off));
        }
    }
}

extern "C" void kernel_launch(void* const* d_in, const int* in_sizes, int n_in,
                              void* d_out, int out_size, void* d_ws, size_t ws_size,
                              hipStream_t stream) {
    const int*   edge_index = (const int*)d_in[0];
    const float* lengths    = (const float*)d_in[1];
    const float* vecs       = (const float*)d_in[2];
    const float* attrs      = (const float*)d_in[3];
    float*       out        = (float*)d_out;

    // 60000 edges / 4 edges-per-wave = 15000 waves; 4 waves/block -> 3750 blocks
    const int blocks = E_CONST / (EPW * 4);
    edge_embed_kernel<<<blocks, 256, 0, stream>>>(edge_index, lengths, vecs, attrs, out);
}

// Round 5
// 606.089 us; speedup vs baseline: 1.0291x; 1.0179x over previous
//
#include <hip/hip_runtime.h>
#include <math.h>

// EdgeEmbeddingBlock: out_r[e,k,n,j] = radial[e,n] * na[sender[e],k] * ylm_r[e,j]
//                     out_i[e,k,n,j] = radial[e,n] * na[sender[e],k] * ylm_i[e,j]
// Constants: E=60000, N_NODES=4000, K_ATTR=10, NMAX=8, J=16 (LMAX=3),
// R_CUT=5, P_CUT=6.  ALL I/O FLOAT32 (edge_index int32).
//
// Output = 614.4 MB pure streaming writes. Harness fill runs 6.2 TB/s; our
// round-3 kernel ~224 us ~= 2.7 TB/s. Round-4 theory: per-wave alternation
// between the r and i streams (307 MB apart) at 1 KiB granularity thrashes
// DRAM rows (~2.3x write-efficiency loss — matches). Fix: SPLIT-GRID STREAM
// SEPARATION — blocks [0,3750) write only the r half, blocks [3750,7500)
// write only the i half (math recomputed per half, ~us-scale cost). Each
// wave writes a 20 KiB contiguous run in ONE stream (4 edges x 5 KiB).
// (Round 4 was an infra failure — this is an unchanged resubmit.)
//
// Per-edge mapping (unchanged, verified): lane covers chunk c = lane+64*it,
// c = k*32 + n*4 + jq with jq=lane&3, n=(lane>>2)&7, kh=lane>>5, k=kh+2*it,
// it=0..4 -> k in [0,10). One dwordx4 nt-store per lane per iter.

#define E_CONST 60000
#define N_NODES 4000
#define K_ATTR 10
#define PER_EDGE 1280   // K_ATTR*8*16
#define EPW 4           // edges per wave
#define HALF_BLOCKS 3750  // E / (EPW * 4 waves/block)

typedef float f32x4 __attribute__((ext_vector_type(4)));

__global__ __launch_bounds__(256) void edge_embed_kernel(
    const int* __restrict__ edge_index,
    const float* __restrict__ lengths,
    const float* __restrict__ vecs,
    const float* __restrict__ attrs,
    float* __restrict__ out)
{
    const int half = (blockIdx.x >= HALF_BLOCKS) ? 1 : 0;   // 0 -> r, 1 -> i
    const int bb   = blockIdx.x - half * HALF_BLOCKS;
    const int wid  = bb * 4 + (threadIdx.x >> 6);
    const int base_e = wid * EPW;
    if (base_e >= E_CONST) return;
    const int lane = threadIdx.x & 63;

    // ---- lane's fixed (jq, n, kh) ----
    const int jq = lane & 3;         // j-quad: j = 4*jq .. 4*jq+3
    const int n  = (lane >> 2) & 7;  // radial index
    const int kh = lane >> 5;        // k = kh + 2*it

    // ---- load ALL 4 edges' scalars first (hide the dependent chains) ----
    float xe[EPW], vxe[EPW], vye[EPW], vze[EPW];
    int snd[EPW];
#pragma unroll
    for (int i = 0; i < EPW; ++i) {
        const int e = base_e + i;
        xe[i]  = lengths[e];
        vxe[i] = vecs[3*e + 0];
        vye[i] = vecs[3*e + 1];
        vze[i] = vecs[3*e + 2];
        int s = edge_index[e];                  // row 0 of (2,E)
        snd[i] = min(max(s, 0), N_NODES - 1);   // safety clamp
    }
    float nae[EPW][5];
#pragma unroll
    for (int i = 0; i < EPW; ++i)
#pragma unroll
        for (int it = 0; it < 5; ++it)
            nae[i][it] = attrs[snd[i] * K_ATTR + (kh + 2 * it)];

    // normalization nlm = sqrt((2l+1)/(4pi) * (l-|m|)!/(l+|m|)!)
    const float n00 = 0.28209479177387814f;
    const float n10 = 0.4886025119029199f,  n11 = 0.34549414947133544f;
    const float n20 = 0.6307831305050401f,  n21 = 0.2575161346821595f,  n22 = 0.12875806798063624f;
    const float n30 = 0.7463526651802308f,  n31 = 0.2154534560075959f,  n32 = 0.06813236509555449f, n33 = 0.027814921575518937f;

    // stream base for this half
    const size_t stream_base = half ? (size_t)E_CONST * PER_EDGE : 0;

#pragma unroll
    for (int i = 0; i < EPW; ++i) {
        const int e = base_e + i;
        const float x = xe[i];

        // ---- radial for this lane's n ----
        const float u  = x * 0.2f;                                // x / R_CUT
        const float u2 = u * u, u3 = u2 * u;
        const float u6 = u3 * u3, u7 = u6 * u, u8 = u7 * u;
        float env = 1.0f - 28.0f * u6 + 48.0f * u7 - 21.0f * u8;  // p=6 poly cutoff
        env = (u < 1.0f) ? env : 0.0f;
        const float PREF = 0.63245553203367586f;                  // sqrt(2/5)
        const float w = (float)(n + 1) * 0.6283185307179586f;     // (n+1)*pi/5
        const float rad = PREF * sinf(w * x) / x * env;

        // ---- unit direction ----
        const float vx = vxe[i], vy = vye[i], vz = vze[i];
        const float nrm = sqrtf(vx*vx + vy*vy + vz*vz);
        const float inv = 1.0f / fmaxf(nrm, 1e-9f);
        const float ux = vx * inv, uy = vy * inv, uz = vz * inv;
        const float z = uz, z2 = z * z;

        // c_m = st^m cos(m phi), s_m = st^m sin(m phi)
        const float c1 = ux,            s1 = uy;
        const float c2 = c1*ux - s1*uy, s2 = s1*ux + c1*uy;
        const float c3 = c2*ux - s2*uy, s3 = s2*ux + c2*uy;

        // Q[l,m] = P[l,m]/st^m (polynomials in z)
        const float Q10 = z;
        const float Q20 = 1.5f*z2 - 0.5f;
        const float Q21 = -3.0f*z;
        const float Q30 = (2.5f*z2 - 1.5f)*z;
        const float Q31 = 1.5f - 7.5f*z2;
        const float Q32 = 15.0f*z;

        // base(l,|m|): br = nlm*Q*c_m, bi = nlm*Q*s_m  (|m| >= 1)
        const float b1r  = n11 * (-1.0f) * c1, b1i  = n11 * (-1.0f) * s1;
        const float b21r = n21 * Q21 * c1,     b21i = n21 * Q21 * s1;
        const float b22r = n22 * 3.0f * c2,    b22i = n22 * 3.0f * s2;
        const float b31r = n31 * Q31 * c1,     b31i = n31 * Q31 * s1;
        const float b32r = n32 * Q32 * c2,     b32i = n32 * Q32 * s2;
        const float b33r = n33 * (-15.0f)*c3,  b33i = n33 * (-15.0f)*s3;

        // j ordering: l=0..3, m=-l..l.  m<0: s=(-1)^|m|, re=s*br, im=-s*bi.
        float yr[16], yi[16];
        yr[0]  =  n00;        yi[0]  =  0.0f;
        yr[1]  = -b1r;        yi[1]  =  b1i;    // (1,-1)
        yr[2]  =  n10 * Q10;  yi[2]  =  0.0f;   // (1, 0)
        yr[3]  =  b1r;        yi[3]  =  b1i;    // (1, 1)
        yr[4]  =  b22r;       yi[4]  = -b22i;   // (2,-2)
        yr[5]  = -b21r;       yi[5]  =  b21i;   // (2,-1)
        yr[6]  =  n20 * Q20;  yi[6]  =  0.0f;   // (2, 0)
        yr[7]  =  b21r;       yi[7]  =  b21i;   // (2, 1)
        yr[8]  =  b22r;       yi[8]  =  b22i;   // (2, 2)
        yr[9]  = -b33r;       yi[9]  =  b33i;   // (3,-3)
        yr[10] =  b32r;       yi[10] = -b32i;   // (3,-2)
        yr[11] = -b31r;       yi[11] =  b31i;   // (3,-1)
        yr[12] =  n30 * Q30;  yi[12] =  0.0f;   // (3, 0)
        yr[13] =  b31r;       yi[13] =  b31i;   // (3, 1)
        yr[14] =  b32r;       yi[14] =  b32i;   // (3, 2)
        yr[15] =  b33r;       yi[15] =  b33i;   // (3, 3)

        // pick this half's component, then the lane's j-quad
        float ys[4];
#pragma unroll
        for (int t = 0; t < 4; ++t) {
            const float v0  = half ? yi[t]      : yr[t];
            const float v1  = half ? yi[4 + t]  : yr[4 + t];
            const float v2  = half ? yi[8 + t]  : yr[8 + t];
            const float v3  = half ? yi[12 + t] : yr[12 + t];
            const float a01 = (jq & 1) ? v1 : v0;
            const float a23 = (jq & 1) ? v3 : v2;
            ys[t] = (jq & 2) ? a23 : a01;
        }

        const size_t base = stream_base + (size_t)e * PER_EDGE;

#pragma unroll
        for (int it = 0; it < 5; ++it) {
            const float s = rad * nae[i][it];
            const int c = lane + 64 * it;              // chunk (4-f32 units)
            const size_t off = (size_t)c * 4;

            f32x4 p;
            p.x = s * ys[0]; p.y = s * ys[1]; p.z = s * ys[2]; p.w = s * ys[3];
            __builtin_nontemporal_store(p, reinterpret_cast<f32x4*>(out + base + off));
        }
    }
}

extern "C" void kernel_launch(void* const* d_in, const int* in_sizes, int n_in,
                              void* d_out, int out_size, void* d_ws, size_t ws_size,
                              hipStream_t stream) {
    const int*   edge_index = (const int*)d_in[0];
    const float* lengths    = (const float*)d_in[1];
    const float* vecs       = (const float*)d_in[2];
    const float* attrs      = (const float*)d_in[3];
    float*       out        = (float*)d_out;

    // 2 halves x 3750 blocks; each block: 4 waves x 4 edges = 16 edges, one stream
    edge_embed_kernel<<<2 * HALF_BLOCKS, 256, 0, stream>>>(edge_index, lengths, vecs, attrs, out);
}